// Round 10
// baseline (122.166 us; speedup 1.0000x reference)
//
#include <hip/hip_runtime.h>
#include <hip/hip_bf16.h>

// Problem constants (match reference)
constexpr int B = 8, T = 64, A = 4, S = 512;
constexpr int V = 32000, EXT_V = 33000;
constexpr int V4 = V / 4;           // 8000 float4s of vocab per row
constexpr int QLEN = 8256;          // floats per quarter q=0..2 (q=3: 8232); /4 aligned
constexpr int Q4 = QLEN / 4;        // 2064 float4s
constexpr int NTH = 512;
constexpr int NBLK = 4 * B * T;     // 2048 blocks (divisible by 8 XCDs)

// LDS-only barrier: cross-thread deps in this kernel are LDS-only
// (zero -> scatter -> read), so wait lgkmcnt(0) and barrier WITHOUT the
// vmcnt(0) drain __syncthreads() would emit. Phase-A global loads (register
// destined, no cross-thread visibility needed) stay in flight across both
// barriers and drain at first use in Phase D via compiler-counted vmcnt.
__device__ __forceinline__ void lds_barrier() {
    asm volatile("s_waitcnt lgkmcnt(0)" ::: "memory");
    __builtin_amdgcn_s_barrier();
}

// Fused scatter+scale, quarter-row split:
//   - 4 blocks per (b,t) row, each privatizing a 33 KB LDS quarter-range
//     -> 4 blocks/CU x 8 waves = 32 waves/CU
//   - ALL global reads issued in Phase A; stream phase is LDS-read+FMA+store
//   - lgkm-only barriers keep vocab loads in flight across phases
//   - XCD-chunked swizzle: one b per XCD; 4 quarters of a bt adjacent
__global__ void __launch_bounds__(NTH, 8)
fused_kernel(const float* __restrict__ vocab,
             const float* __restrict__ gen,
             const float* __restrict__ attn,
             const float* __restrict__ agent_attn,
             const int* __restrict__ article,
             float* __restrict__ out) {
    __shared__ float smem[QLEN];    // 33 024 B -> 4 blocks/CU
    constexpr int PER_XCD = NBLK / 8;          // 256
    const int l = (blockIdx.x & 7) * PER_XCD + (blockIdx.x >> 3);  // bijective
    const int bt = l >> 2;
    const int q  = l & 3;
    const int vbase = q * QLEN;
    const int vlen  = (q == 3) ? (EXT_V - 3 * QLEN) : QLEN;   // 8232 : 8256
    const int vlen4 = vlen >> 2;                              // 2058 : 2064
    const int b = bt / T;
    const int tid = threadIdx.x;

    // ---- Phase A: issue ALL global reads ----
    // scatter pair k has a=k, s=tid (since S == NTH == 512): coalesced
    int   sidx[4];
    float sval[4];
#pragma unroll
    for (int k = 0; k < A; ++k) {
        sidx[k] = article[(b * A + k) * S + tid] - vbase;
        sval[k] = attn[(size_t)(bt * A + k) * S + tid];
    }
    float coef = 0.f;
    float wA[4];
#pragma unroll
    for (int k = 0; k < A; ++k) {
        const float g  = gen[bt * A + k];
        const float aa = agent_attn[bt * A + k];
        coef += aa * g;
        wA[k] = aa * (1.0f - g);
    }
#pragma unroll
    for (int k = 0; k < A; ++k) sval[k] *= wA[k];

    // vocab prefetch: the thread's entire quarter slice (4 float4 + remainder)
    const float4* __restrict__ vrow = reinterpret_cast<const float4*>(vocab + (size_t)bt * V);
    const int g4base = vbase >> 2;
    float4 p[4];
#pragma unroll
    for (int k = 0; k < 4; ++k) {
        const int gi = g4base + tid + k * NTH;
        p[k] = (gi < V4) ? vrow[gi] : make_float4(0.f, 0.f, 0.f, 0.f);
    }
    const int irem = 4 * NTH + tid;            // 2048 + tid
    const bool has_rem = irem < vlen4;         // 16 threads (q<3) / 10 (q=3)
    float4 prem = make_float4(0.f, 0.f, 0.f, 0.f);
    if (has_rem && (g4base + irem) < V4) prem = vrow[g4base + irem];

    // ---- Phase B: zero the LDS quarter (global loads above stay in flight) ----
    float4* s4 = reinterpret_cast<float4*>(smem);
#pragma unroll
    for (int k = 0; k < 4; ++k)
        s4[tid + k * NTH] = make_float4(0.f, 0.f, 0.f, 0.f);
    if (tid < Q4 - 4 * NTH)                    // last 16 float4s
        s4[4 * NTH + tid] = make_float4(0.f, 0.f, 0.f, 0.f);
    lds_barrier();

    // ---- Phase C: LDS scatter from registers ----
#pragma unroll
    for (int k = 0; k < A; ++k)
        if ((unsigned)sidx[k] < (unsigned)vlen)
            atomicAdd(smem + sidx[k], sval[k]);
    lds_barrier();

    // ---- Phase D: stream: out = prefetched vocab*coef + lds ----
    float4* __restrict__ orow = reinterpret_cast<float4*>(out + (size_t)bt * EXT_V);
#pragma unroll
    for (int k = 0; k < 4; ++k) {
        const int i = tid + k * NTH;
        float4 r = s4[i];
        r.x += p[k].x * coef; r.y += p[k].y * coef;
        r.z += p[k].z * coef; r.w += p[k].w * coef;
        orow[g4base + i] = r;
    }
    if (has_rem) {
        float4 r = s4[irem];
        r.x += prem.x * coef; r.y += prem.y * coef;
        r.z += prem.z * coef; r.w += prem.w * coef;
        orow[g4base + irem] = r;
    }
}

extern "C" void kernel_launch(void* const* d_in, const int* in_sizes, int n_in,
                              void* d_out, int out_size, void* d_ws, size_t ws_size,
                              hipStream_t stream) {
    const float* vocab      = (const float*)d_in[0];  // [B,T,V]
    const float* gen        = (const float*)d_in[1];  // [B,T,A]
    const float* attn       = (const float*)d_in[2];  // [B,T,A,S]
    const float* agent_attn = (const float*)d_in[3];  // [B,T,A]
    const int*   article    = (const int*)d_in[4];    // [B,A,S]
    float* out = (float*)d_out;                       // [B,T,EXT_V]

    fused_kernel<<<NBLK, NTH, 0, stream>>>(vocab, gen, attn, agent_attn, article, out);
}